// Round 2
// baseline (165.022 us; speedup 1.0000x reference)
//
#include <hip/hip_runtime.h>

#define HID 20

typedef float v2f __attribute__((ext_vector_type(2)));

// Native-instruction SiLU on a packed pair. exp/rcp are scalar trans ops
// (quarter-rate); surrounding muls pack as v_pk_*. Formula kept bit-identical
// to the previous kernel (same constant, same op order per scalar lane).
__device__ __forceinline__ v2f silu2(v2f a) {
    v2f s = a * (-1.442695040888963f);        // one v_pk_mul_f32
    float e0 = __builtin_amdgcn_exp2f(s.x);   // exp(-a0)
    float e1 = __builtin_amdgcn_exp2f(s.y);   // exp(-a1)
    v2f rc;
    rc.x = __builtin_amdgcn_rcpf(1.0f + e0);
    rc.y = __builtin_amdgcn_rcpf(1.0f + e1);
    return a * rc;                            // one v_pk_mul_f32
}

// 20->20 layer on a pair of points, j-blocked by JB with i as the middle
// loop (R4: 4 independent acc chains -> dep distance covers pk_fma latency).
// R5: weights/biases now come from LDS. Rationale: with weights in SGPRs the
// 102-SGPR budget left zero room to prefetch the next j-block (84 floats), so
// every block exposed ~220cy of s_load latency in lockstep across all waves
// (VALUBusy stuck at 72%, idle ~= 32 blocks x 220cy). LDS reads issue on the
// lgkm pipe (no VALU slots), latency ~120cy, and prefetch depth lives in the
// ~84 free VGPRs. Wave-uniform LDS address = broadcast, no bank conflicts.
template <int JB>
__device__ __forceinline__ void layer20(const float* __restrict__ W,
                                        const float* __restrict__ b,
                                        const v2f* __restrict__ h,
                                        v2f* __restrict__ hn) {
    static_assert(HID % JB == 0, "JB must divide HID");
    #pragma unroll
    for (int jb = 0; jb < HID; jb += JB) {
        v2f acc[JB];
        #pragma unroll
        for (int j = 0; j < JB; ++j) {
            float bj = b[jb + j];
            acc[j] = (v2f){bj, bj};
        }
        #pragma unroll
        for (int i = 0; i < HID; ++i) {
            v2f hi = h[i];
            #pragma unroll
            for (int j = 0; j < JB; ++j) {
                float w = W[(jb + j) * HID + i];
                acc[j] = __builtin_elementwise_fma(hi, (v2f){w, w}, acc[j]);
            }
        }
        #pragma unroll
        for (int j = 0; j < JB; ++j)
            hn[jb + j] = silu2(acc[j]);
    }
}

// LDS layout: [W0(20) b0(20)] [W1(400) b1(20)] x6 [W7(20) b7(1)] = 2581 f.
#define L0_W 0
#define L0_B 20
#define LYR(l) (40 + ((l) - 1) * 420)   // l in 1..6 -> W at LYR, b at LYR+400
#define L7_W (40 + 6 * 420)             // 2560
#define L7_B (L7_W + 20)                // 2580
#define S_TOT 2581

__global__ __launch_bounds__(256, 4) void SpringEquationNN_70102456205450_kernel(
    const float* __restrict__ t,
    const float* __restrict__ W0, const float* __restrict__ b0,
    const float* __restrict__ W1, const float* __restrict__ b1,
    const float* __restrict__ W2, const float* __restrict__ b2,
    const float* __restrict__ W3, const float* __restrict__ b3,
    const float* __restrict__ W4, const float* __restrict__ b4,
    const float* __restrict__ W5, const float* __restrict__ b5,
    const float* __restrict__ W6, const float* __restrict__ b6,
    const float* __restrict__ W7, const float* __restrict__ b7,
    float* __restrict__ out, int n)
{
    __shared__ float s[S_TOT];

    // Cooperative stage of all weights/biases (10.3 KB, once per workgroup).
    {
        const float* srcs[16] = {W0, b0, W1, b1, W2, b2, W3, b3,
                                 W4, b4, W5, b5, W6, b6, W7, b7};
        const int offs[16] = {L0_W, L0_B,
                              LYR(1), LYR(1) + 400, LYR(2), LYR(2) + 400,
                              LYR(3), LYR(3) + 400, LYR(4), LYR(4) + 400,
                              LYR(5), LYR(5) + 400, LYR(6), LYR(6) + 400,
                              L7_W, L7_B};
        const int cnts[16] = {20, 20, 400, 20, 400, 20, 400, 20,
                              400, 20, 400, 20, 400, 20, 20, 1};
        #pragma unroll
        for (int a = 0; a < 16; ++a)
            for (int k = threadIdx.x; k < cnts[a]; k += 256)
                s[offs[a] + k] = srcs[a][k];
    }
    __syncthreads();

    int idx = blockIdx.x * blockDim.x + threadIdx.x;   // pair index
    int p0 = 2 * idx;
    if (p0 >= n) return;

    // Coalesced 8B load of two consecutive points (N is even: 1048576).
    v2f x = *(const v2f*)(t + p0);

    v2f h[HID], hn[HID];

    // Layer 0: 1 -> 20 on both points
    #pragma unroll
    for (int j = 0; j < HID; ++j) {
        float w = s[L0_W + j], bb = s[L0_B + j];
        v2f a = __builtin_elementwise_fma(x, (v2f){w, w}, (v2f){bb, bb});
        h[j] = silu2(a);
    }

    // Layers 1..6: 20 -> 20, SiLU
    layer20<4>(s + LYR(1), s + LYR(1) + 400, h, hn);
    layer20<4>(s + LYR(2), s + LYR(2) + 400, hn, h);
    layer20<4>(s + LYR(3), s + LYR(3) + 400, h, hn);
    layer20<4>(s + LYR(4), s + LYR(4) + 400, hn, h);
    layer20<4>(s + LYR(5), s + LYR(5) + 400, h, hn);
    layer20<4>(s + LYR(6), s + LYR(6) + 400, hn, h);

    // Layer 7: 20 -> 1 (no activation). Single serial chain in ascending-i
    // order to preserve the exact reference summation order.
    float b7v = s[L7_B];
    v2f acc = {b7v, b7v};
    #pragma unroll
    for (int i = 0; i < HID; ++i) {
        float w = s[L7_W + i];
        acc = __builtin_elementwise_fma(h[i], (v2f){w, w}, acc);
    }

    // Coalesced 8B store.
    *(v2f*)(out + p0) = acc;
}

extern "C" void kernel_launch(void* const* d_in, const int* in_sizes, int n_in,
                              void* d_out, int out_size, void* d_ws, size_t ws_size,
                              hipStream_t stream) {
    const float* t  = (const float*)d_in[0];
    const float* W0 = (const float*)d_in[1];
    const float* b0 = (const float*)d_in[2];
    const float* W1 = (const float*)d_in[3];
    const float* b1 = (const float*)d_in[4];
    const float* W2 = (const float*)d_in[5];
    const float* b2 = (const float*)d_in[6];
    const float* W3 = (const float*)d_in[7];
    const float* b3 = (const float*)d_in[8];
    const float* W4 = (const float*)d_in[9];
    const float* b4 = (const float*)d_in[10];
    const float* W5 = (const float*)d_in[11];
    const float* b5 = (const float*)d_in[12];
    const float* W6 = (const float*)d_in[13];
    const float* b6 = (const float*)d_in[14];
    const float* W7 = (const float*)d_in[15];
    const float* b7 = (const float*)d_in[16];
    float* out = (float*)d_out;

    int n = in_sizes[0];             // N points
    int pairs = (n + 1) / 2;         // threads (N=1048576 -> 524288)
    int block = 256;
    int grid = (pairs + block - 1) / block;
    SpringEquationNN_70102456205450_kernel<<<grid, block, 0, stream>>>(
        t, W0, b0, W1, b1, W2, b2, W3, b3, W4, b4, W5, b5, W6, b6, W7, b7,
        out, n);
}

// Round 3
// 162.186 us; speedup vs baseline: 1.0175x; 1.0175x over previous
//
#include <hip/hip_runtime.h>

#define HID 20

typedef float v2f __attribute__((ext_vector_type(2)));
typedef float v4f __attribute__((ext_vector_type(4)));

// SiLU on a packed pair (two outputs of ONE point). exp/rcp are scalar trans
// ops; formula and op order bit-identical to R0/R1 per scalar lane.
__device__ __forceinline__ v2f silu2(v2f a) {
    v2f s = a * (-1.442695040888963f);
    float e0 = __builtin_amdgcn_exp2f(s.x);
    float e1 = __builtin_amdgcn_exp2f(s.y);
    v2f rc;
    rc.x = __builtin_amdgcn_rcpf(1.0f + e0);
    rc.y = __builtin_amdgcn_rcpf(1.0f + e1);
    return a * rc;
}

// acc.{lo,hi} += w.{lo,hi} * h.HALF  -- ONE v_pk_fma_f32.
// R3 rationale: R1's VGPR_Count=44 proves the compiler scalarized the v2f
// dataflow and fissioned the two points (h[20] alone needs 40 VGPRs when
// packed) -> every FMA issued twice. Inline asm forces the packed form.
// The weight is the packed operand (j-pair); the activation scalar is
// broadcast from its resident v2f pair via op_sel -- zero mov overhead.
template <int HALF>
__device__ __forceinline__ void pkfma_bcast(v2f& acc, v2f w, v2f h) {
    if constexpr (HALF == 0)
        asm("v_pk_fma_f32 %0, %1, %2, %0 op_sel:[0,0,0] op_sel_hi:[1,0,1]"
            : "+v"(acc) : "v"(w), "v"(h));
    else
        asm("v_pk_fma_f32 %0, %1, %2, %0 op_sel:[0,1,0] op_sel_hi:[1,1,1]"
            : "+v"(acc) : "v"(w), "v"(h));
}

// 20->20 layer, two points per thread. Activations are stored j-paired per
// point (hp0[i>>1] half (i&1) = h_i of point 0). Weights come transposed
// from LDS: wt[i*20+j] = W[j][i], so a ds_read_b128 yields W[j..j+3][i] --
// 21 LDS reads per 4-output block (vs 420 scalar reads in the R2 design).
// 4 independent acc chains (a0..a3) give dep distance 8cy >= pk_fma latency.
// Summation per output: bias init + ascending-i fma = bit-exact vs R0/R1.
__device__ __forceinline__ void layer20(const float* __restrict__ wt,
                                        const float* __restrict__ bl,
                                        const v2f* __restrict__ hp0,
                                        const v2f* __restrict__ hp1,
                                        v2f* __restrict__ on0,
                                        v2f* __restrict__ on1) {
    #pragma unroll
    for (int jp = 0; jp < HID / 2; jp += 2) {
        v4f bw = *(const v4f*)(bl + 2 * jp);      // biases j..j+3 (16B aligned)
        v2f a0 = bw.xy, a1 = bw.xy;               // outs (2jp,2jp+1), pt0/pt1
        v2f a2 = bw.zw, a3 = bw.zw;               // outs (2jp+2,2jp+3), pt0/pt1
        #pragma unroll
        for (int i = 0; i < HID; ++i) {
            v4f w = *(const v4f*)(wt + i * HID + 2 * jp);  // W[2jp..2jp+3][i]
            v2f w01 = w.xy, w23 = w.zw;           // subreg pairs, no movs
            v2f h0 = hp0[i >> 1], h1 = hp1[i >> 1];
            if ((i & 1) == 0) {
                pkfma_bcast<0>(a0, w01, h0);
                pkfma_bcast<0>(a1, w01, h1);
                pkfma_bcast<0>(a2, w23, h0);
                pkfma_bcast<0>(a3, w23, h1);
            } else {
                pkfma_bcast<1>(a0, w01, h0);
                pkfma_bcast<1>(a1, w01, h1);
                pkfma_bcast<1>(a2, w23, h0);
                pkfma_bcast<1>(a3, w23, h1);
            }
        }
        on0[jp]     = silu2(a0);
        on1[jp]     = silu2(a1);
        on0[jp + 1] = silu2(a2);
        on1[jp + 1] = silu2(a3);
    }
}

#define LSTRIDE 420   // 400 transposed weights + 20 biases per layer

__global__ __launch_bounds__(256, 4) void SpringEquationNN_70102456205450_kernel(
    const float* __restrict__ t,
    const float* __restrict__ W0, const float* __restrict__ b0,
    const float* __restrict__ W1, const float* __restrict__ b1,
    const float* __restrict__ W2, const float* __restrict__ b2,
    const float* __restrict__ W3, const float* __restrict__ b3,
    const float* __restrict__ W4, const float* __restrict__ b4,
    const float* __restrict__ W5, const float* __restrict__ b5,
    const float* __restrict__ W6, const float* __restrict__ b6,
    const float* __restrict__ W7, const float* __restrict__ b7,
    float* __restrict__ out, int n)
{
    __shared__ float s[6 * LSTRIDE];

    // Stage W1..W6 TRANSPOSED (+ biases) into LDS, once per block (10.1 KB).
    {
        const float* Ws[6] = {W1, W2, W3, W4, W5, W6};
        const float* bs[6] = {b1, b2, b3, b4, b5, b6};
        #pragma unroll
        for (int l = 0; l < 6; ++l) {
            float* base = s + l * LSTRIDE;
            for (int k = threadIdx.x; k < 400; k += 256) {
                int j = k / HID, i = k - j * HID;
                base[i * HID + j] = Ws[l][k];     // wt[i][j] = W[j][i]
            }
            if (threadIdx.x < HID) base[400 + threadIdx.x] = bs[l][threadIdx.x];
        }
    }
    __syncthreads();

    int idx = blockIdx.x * blockDim.x + threadIdx.x;   // pair index
    int p0 = 2 * idx;
    if (p0 >= n) return;

    v2f x = *(const v2f*)(t + p0);   // two consecutive points, 8B coalesced

    // Activations, j-paired per point: hX[jp] = {h_{2jp}, h_{2jp+1}} of pt X.
    v2f h0[HID / 2], h1[HID / 2], g0[HID / 2], g1[HID / 2];

    // Layer 0: 1 -> 20 on both points (small; W0/b0 via scalar loads).
    #pragma unroll
    for (int jp = 0; jp < HID / 2; ++jp) {
        float wA = W0[2 * jp], wB = W0[2 * jp + 1];
        float bA = b0[2 * jp], bB = b0[2 * jp + 1];
        v2f aP0 = {__builtin_fmaf(x.x, wA, bA), __builtin_fmaf(x.x, wB, bB)};
        v2f aP1 = {__builtin_fmaf(x.y, wA, bA), __builtin_fmaf(x.y, wB, bB)};
        h0[jp] = silu2(aP0);
        h1[jp] = silu2(aP1);
    }

    // Layers 1..6: 20 -> 20, SiLU (ping-pong h<->g, ends back in h).
    layer20(s + 0 * LSTRIDE, s + 0 * LSTRIDE + 400, h0, h1, g0, g1);
    layer20(s + 1 * LSTRIDE, s + 1 * LSTRIDE + 400, g0, g1, h0, h1);
    layer20(s + 2 * LSTRIDE, s + 2 * LSTRIDE + 400, h0, h1, g0, g1);
    layer20(s + 3 * LSTRIDE, s + 3 * LSTRIDE + 400, g0, g1, h0, h1);
    layer20(s + 4 * LSTRIDE, s + 4 * LSTRIDE + 400, h0, h1, g0, g1);
    layer20(s + 5 * LSTRIDE, s + 5 * LSTRIDE + 400, g0, g1, h0, h1);

    // Layer 7: 20 -> 1 per point, serial ascending-i chain (bit-exact order).
    float b7v = b7[0];
    float accA = b7v, accB = b7v;
    #pragma unroll
    for (int i = 0; i < HID; ++i) {
        float w = W7[i];
        float hA = (i & 1) ? h0[i >> 1].y : h0[i >> 1].x;
        float hB = (i & 1) ? h1[i >> 1].y : h1[i >> 1].x;
        accA = __builtin_fmaf(hA, w, accA);
        accB = __builtin_fmaf(hB, w, accB);
    }

    *(v2f*)(out + p0) = (v2f){accA, accB};   // 8B coalesced store
}

extern "C" void kernel_launch(void* const* d_in, const int* in_sizes, int n_in,
                              void* d_out, int out_size, void* d_ws, size_t ws_size,
                              hipStream_t stream) {
    const float* t  = (const float*)d_in[0];
    const float* W0 = (const float*)d_in[1];
    const float* b0 = (const float*)d_in[2];
    const float* W1 = (const float*)d_in[3];
    const float* b1 = (const float*)d_in[4];
    const float* W2 = (const float*)d_in[5];
    const float* b2 = (const float*)d_in[6];
    const float* W3 = (const float*)d_in[7];
    const float* b3 = (const float*)d_in[8];
    const float* W4 = (const float*)d_in[9];
    const float* b4 = (const float*)d_in[10];
    const float* W5 = (const float*)d_in[11];
    const float* b5 = (const float*)d_in[12];
    const float* W6 = (const float*)d_in[13];
    const float* b6 = (const float*)d_in[14];
    const float* W7 = (const float*)d_in[15];
    const float* b7 = (const float*)d_in[16];
    float* out = (float*)d_out;

    int n = in_sizes[0];             // N points
    int pairs = (n + 1) / 2;         // threads (N=1048576 -> 524288)
    int block = 256;
    int grid = (pairs + block - 1) / block;
    SpringEquationNN_70102456205450_kernel<<<grid, block, 0, stream>>>(
        t, W0, b0, W1, b1, W2, b2, W3, b3, W4, b4, W5, b5, W6, b6, W7, b7,
        out, n);
}